// Round 22
// baseline (17.702 us; speedup 1.0000x reference)
//
#include <hip/hip_runtime.h>

#define BB 4
#define RR 160
#define HH 128
#define WW 128
#define CC 64
#define NREG 32
#define PH 7
#define PW 7
#define IOU_THRF 0.4f

// floor division (Python // semantics) for possibly-negative numerators
__device__ __forceinline__ int fdiv(int a, int b) {
    int q = a / b, r = a % b;
    return (r != 0 && ((r < 0) != (b < 0))) ? q - 1 : q;
}

__device__ __forceinline__ void fix_span(int& lo, int& hi, int p, int s) {
    int pad = p - (hi - lo);
    bool fmin = lo < fdiv(pad, 2);
    bool fmax = (s - hi) < fdiv(1 + pad, 2);
    bool sym = (pad > 0) && !(fmin || fmax);
    int lo2 = sym ? lo - fdiv(pad, 2) : lo;
    int hi2 = sym ? hi + fdiv(1 + pad, 2) : hi;
    if ((pad > 0) && fmin) { lo2 = 0; hi2 = p; }
    if ((pad > 0) && fmax) { lo2 = s - p; hi2 = s; }
    lo = lo2; hi = hi2;
}

__device__ __forceinline__ float4 fmax4(float4 a, float4 b) {
    a.x = fmaxf(a.x, b.x); a.y = fmaxf(a.y, b.y);
    a.z = fmaxf(a.z, b.z); a.w = fmaxf(a.w, b.w);
    return a;
}

// Ballot build for suppression word w, rows [tlo,thi).
__device__ __forceinline__ void build_rows(int w, int tlo, int thi, int lane,
                                           const float* sx, const float* sy,
                                           const float* sx1, const float* sy1,
                                           const float* sarea,
                                           unsigned long long (*nsup)[3]) {
    const int j  = w * 64 + lane;
    const int jc = j < RR ? j : RR - 1;
    const float jx0 = sx[jc], jy0 = sy[jc], jx1 = sx1[jc], jy1 = sy1[jc], ja = sarea[jc];
    const bool jok = j < RR;

    #pragma unroll 4
    for (int t = tlo; t < thi; ++t) {
        const float xa = fmaxf(sx[t], jx0);
        const float ya = fmaxf(sy[t], jy0);
        const float xb = fminf(sx1[t], jx1);
        const float yb = fminf(sy1[t], jy1);
        const float iw  = fmaxf(__fsub_rn(xb, xa), 0.0f);
        const float ihh = fmaxf(__fsub_rn(yb, ya), 0.0f);
        const float inter = __fmul_rn(iw, ihh);
        const float denom = __fsub_rn(__fadd_rn(sarea[t], ja), inter);
        const bool pred = jok && (j > t) && (__fdiv_rn(inter, denom) > IOU_THRF);
        const unsigned long long bal = __ballot(pred);
        if (lane == 0) nsup[t][w] = ~bal;
    }
}

// R21 NMS, verbatim: k0-only phase-1 build, wave-0-only early-exit scan,
// lazy phases 2/3 on the (unobserved) not-done path.
__global__ __launch_bounds__(1024)
void nms_clip_kernel(const float* __restrict__ roi, int* __restrict__ boxes_out) {
    const int b = blockIdx.x;
    const int tid = threadIdx.x;
    const int wid = tid >> 6;
    const int lane = tid & 63;

    __shared__ float sx[RR], sy[RR], sx1[RR], sy1[RR], sarea[RR];
    __shared__ unsigned long long nsup[RR][3];   // ~suppression words
    __shared__ int sdone;

    const float* rb = roi + (size_t)b * RR * 4;
    if (tid < RR) {
        const float4 r4 = reinterpret_cast<const float4*>(rb)[tid];
        sx[tid] = r4.x; sy[tid] = r4.y;
        sx1[tid] = __fadd_rn(r4.x, r4.z);
        sy1[tid] = __fadd_rn(r4.y, r4.w);
        sarea[tid] = __fmul_rn(r4.z, r4.w);
    }
    __syncthreads();

    // ---- phase 1 build: word 0 ONLY, rows [0,64): 16 waves x 4 rows ----
    build_rows(0, wid * 4, wid * 4 + 4, lane, sx, sy, sx1, sy1, sarea, nsup);
    __syncthreads();

    unsigned long long k0 = ~0ull, k1 = ~0ull, k2 = (1ull << 32) - 1;

    // ---- scan word 0, k0 only, WAVE 0 only ----
    if (wid == 0) {
        bool done = false;
        for (int tb = 0; tb < 64 && !done; tb += 8) {
            #pragma unroll
            for (int t0 = 0; t0 < 8; ++t0) {
                const int t = tb + t0;
                unsigned long long mb = ((k0 >> t) & 1ull) - 1ull;
                k0 &= nsup[t][0] | mb;
            }
            const unsigned long long pfx =
                (tb + 8 >= 64) ? ~0ull : ((1ull << (tb + 8)) - 1ull);
            if (__popcll(k0 & pfx) >= NREG) { k0 &= pfx; done = true; }
        }
        if (lane == 0) sdone = done ? 1 : 0;
    }
    __syncthreads();

    const int d0 = sdone;               // block-uniform
    if (d0) {
        k1 = 0; k2 = 0;                 // never read on the select path anyway
    } else {
        // ---- rare path. phase 2 build: rows [0,128) x words {1,2} ----
        {
            int w, tlo;
            if (wid < 8) { w = 1; tlo = wid * 16; }
            else         { w = 2; tlo = (wid - 8) * 16; }
            build_rows(w, tlo, tlo + 16, lane, sx, sy, sx1, sy1, sarea, nsup);
        }
        __syncthreads();

        if (wid == 0) {
            // exact k1/k2 reconstruction from FINAL k0 (linear, prefetchable)
            #pragma unroll 8
            for (int t = 0; t < 64; ++t) {
                unsigned long long mb = ((k0 >> t) & 1ull) - 1ull;
                k1 &= nsup[t][1] | mb;
                k2 &= nsup[t][2] | mb;
            }
            // scan word 1 with early exit
            bool done = false;
            const int cnt0 = __popcll(k0);
            for (int tb = 64; tb < 128 && !done; tb += 8) {
                #pragma unroll
                for (int t0 = 0; t0 < 8; ++t0) {
                    const int t = tb + t0;
                    unsigned long long mb = ((k1 >> (t - 64)) & 1ull) - 1ull;
                    k1 &= nsup[t][1] | mb;
                    k2 &= nsup[t][2] | mb;
                }
                const unsigned long long pfx =
                    (tb - 64 + 8 >= 64) ? ~0ull : ((1ull << (tb - 64 + 8)) - 1ull);
                if (cnt0 + __popcll(k1 & pfx) >= NREG) { k1 &= pfx; k2 = 0; done = true; }
            }
            if (lane == 0) sdone = done ? 1 : 0;
        }
        __syncthreads();

        const int d1 = sdone;           // block-uniform
        if (!d1) {
            // ---- phase 3 build: rows [128,159) word 2; 2 rows/wave ----
            {
                const int tlo = 128 + wid * 2;
                const int thi = min(tlo + 2, 159);
                if (tlo < 159)
                    build_rows(2, tlo, thi, lane, sx, sy, sx1, sy1, sarea, nsup);
            }
            __syncthreads();

            if (wid == 0) {
                bool done = false;
                const int cnt01 = __popcll(k0) + __popcll(k1);
                for (int tb = 128; tb < 159 && !done; tb += 8) {
                    const int te = (tb + 8 < 159) ? tb + 8 : 159;
                    for (int t = tb; t < te; ++t) {
                        unsigned long long mb = ((k2 >> (t - 128)) & 1ull) - 1ull;
                        k2 &= nsup[t][2] | mb;
                    }
                    const unsigned long long pfx =
                        ((te - 128) >= 64) ? ~0ull : ((1ull << (te - 128)) - 1ull);
                    if (cnt01 + __popcll(k2 & pfx) >= NREG) { k2 &= pfx; done = true; }
                }
            }
        }
    }

    if (tid >= NREG) return;            // select threads are all in wave 0

    // select the tid-th kept box (pad: box RR-1)
    int src = RR - 1;
    {
        int target = tid;
        unsigned long long words[3] = {k0, k1, k2};
        #pragma unroll
        for (int w = 0; w < 3; ++w) {
            int pc = __popcll(words[w]);
            if (target < pc) {
                unsigned long long x = words[w];
                for (int q = 0; q < target; ++q) x &= x - 1;
                src = w * 64 + (__ffsll((long long)x) - 1);
                break;
            }
            target -= pc;
        }
    }

    int x0 = max(0, (int)sx[src]);
    int y0 = max(0, (int)sy[src]);
    int x1 = min(WW, (int)sx1[src]);
    int y1 = min(HH, (int)sy1[src]);
    fix_span(x0, x1, PW, WW);
    fix_span(y0, y1, PH, HH);
    int* o = boxes_out + ((size_t)b * NREG + tid) * 4;
    o[0] = x0; o[1] = y0; o[2] = x1 - x0; o[3] = y1 - y0;
}

// Pool v3 (ILP-8): 8 independent temps + 8 independent accumulators per
// 8-row chunk -> serialized load-rounds per wave drop from ng*ceil(nr/4) to
// ng*ceil(nr/8) (nr<=10 -> <=2 chunks/group). Clamp duplicates are
// same-cacheline L1 hits OFF the dependency chain (unlike R7's chained
// 6-group inflation). All indexing static (rule #20).
__global__ __launch_bounds__(PW * CC)
void pool_kernel(const float* __restrict__ feat, const int* __restrict__ boxes,
                 float* __restrict__ out) {
    // bijective XCD decode: xcd x = g%8 owns (b,n) pairs [x*16, x*16+16)
    const int g = blockIdx.x;
    const int x = g & 7;
    const int q = g >> 3;
    const int pair = x * 16 + q / 7;
    const int i = q % 7;
    const int n = pair & (NREG - 1);
    const int b = pair >> 5;

    const int wave = threadIdx.x >> 6;   // jj, 0..6 (wave-uniform)
    const int lane = threadIdx.x & 63;
    const int poff = lane >> 4;          // 0..3 pixel offset within group
    const int cq   = lane & 15;          // 0..15 channel quad

    const int4 bx = *reinterpret_cast<const int4*>(boxes + ((size_t)b * NREG + n) * 4);
    const int x0 = bx.x, y0 = bx.y, w = bx.z, h = bx.w;
    const int hs = h / PH, wsz = w / PW;

    const int r0 = y0 + i * hs;
    const int r1 = (i == PH - 1) ? (y0 + h) : (r0 + hs);
    const int c0 = x0 + wave * wsz;
    const int c1 = (wave == PW - 1) ? (x0 + w) : (c0 + wsz);
    const int nr = r1 - r0;              // 1..10
    const int ng = (c1 - c0 + 3) >> 2;   // 1..4 column groups

    const float* fb = feat + (size_t)b * HH * WW * CC + (size_t)cq * 4;

    const float4 NEG = make_float4(-INFINITY, -INFINITY, -INFINITY, -INFINITY);
    float4 a0 = NEG, a1 = NEG, a2 = NEG, a3 = NEG;
    float4 a4 = NEG, a5 = NEG, a6 = NEG, a7 = NEG;

    for (int gg = 0; gg < ng; ++gg) {
        int px = c0 + (gg << 2) + poff;
        px = px < c1 ? px : c1 - 1;
        const float* colp = fb + (size_t)px * CC;
        for (int rr = 0; rr < nr; rr += 8) {
            const int q1 = min(rr + 1, nr - 1);
            const int q2 = min(rr + 2, nr - 1);
            const int q3 = min(rr + 3, nr - 1);
            const int q4 = min(rr + 4, nr - 1);
            const int q5 = min(rr + 5, nr - 1);
            const int q6 = min(rr + 6, nr - 1);
            const int q7 = min(rr + 7, nr - 1);
            const float4 t0 = *reinterpret_cast<const float4*>(colp + (size_t)(r0 + rr) * (WW * CC));
            const float4 t1 = *reinterpret_cast<const float4*>(colp + (size_t)(r0 + q1) * (WW * CC));
            const float4 t2 = *reinterpret_cast<const float4*>(colp + (size_t)(r0 + q2) * (WW * CC));
            const float4 t3 = *reinterpret_cast<const float4*>(colp + (size_t)(r0 + q3) * (WW * CC));
            const float4 t4 = *reinterpret_cast<const float4*>(colp + (size_t)(r0 + q4) * (WW * CC));
            const float4 t5 = *reinterpret_cast<const float4*>(colp + (size_t)(r0 + q5) * (WW * CC));
            const float4 t6 = *reinterpret_cast<const float4*>(colp + (size_t)(r0 + q6) * (WW * CC));
            const float4 t7 = *reinterpret_cast<const float4*>(colp + (size_t)(r0 + q7) * (WW * CC));
            a0 = fmax4(a0, t0);
            a1 = fmax4(a1, t1);
            a2 = fmax4(a2, t2);
            a3 = fmax4(a3, t3);
            a4 = fmax4(a4, t4);
            a5 = fmax4(a5, t5);
            a6 = fmax4(a6, t6);
            a7 = fmax4(a7, t7);
        }
    }
    float4 v = fmax4(fmax4(fmax4(a0, a1), fmax4(a2, a3)),
                     fmax4(fmax4(a4, a5), fmax4(a6, a7)));

    // reduce over the 4 pixel-groups: lanes {cq, cq+16, cq+32, cq+48}
    v.x = fmaxf(v.x, __shfl_xor(v.x, 16));
    v.y = fmaxf(v.y, __shfl_xor(v.y, 16));
    v.z = fmaxf(v.z, __shfl_xor(v.z, 16));
    v.w = fmaxf(v.w, __shfl_xor(v.w, 16));
    v.x = fmaxf(v.x, __shfl_xor(v.x, 32));
    v.y = fmaxf(v.y, __shfl_xor(v.y, 32));
    v.z = fmaxf(v.z, __shfl_xor(v.z, 32));
    v.w = fmaxf(v.w, __shfl_xor(v.w, 32));

    if (poff == 0) {
        float4* o = reinterpret_cast<float4*>(
            out + ((((size_t)b * NREG + n) * PH + i) * PW + wave) * CC) + cq;
        *o = v;
    }
}

extern "C" void kernel_launch(void* const* d_in, const int* in_sizes, int n_in,
                              void* d_out, int out_size, void* d_ws, size_t ws_size,
                              hipStream_t stream) {
    const float* features = (const float*)d_in[0];
    const float* roi      = (const float*)d_in[1];
    float* out = (float*)d_out;
    int* boxes = (int*)d_ws;   // BB*NREG*4 ints = 2 KB

    nms_clip_kernel<<<BB, 1024, 0, stream>>>(roi, boxes);
    pool_kernel<<<BB * NREG * PH, PW * CC, 0, stream>>>(features, boxes, out);
}

// Round 23
// 16.767 us; speedup vs baseline: 1.0557x; 1.0557x over previous
//
#include <hip/hip_runtime.h>

#define BB 4
#define RR 160
#define HH 128
#define WW 128
#define CC 64
#define NREG 32
#define PH 7
#define PW 7
#define IOU_THRF 0.4f

// floor division (Python // semantics) for possibly-negative numerators
__device__ __forceinline__ int fdiv(int a, int b) {
    int q = a / b, r = a % b;
    return (r != 0 && ((r < 0) != (b < 0))) ? q - 1 : q;
}

__device__ __forceinline__ void fix_span(int& lo, int& hi, int p, int s) {
    int pad = p - (hi - lo);
    bool fmin = lo < fdiv(pad, 2);
    bool fmax = (s - hi) < fdiv(1 + pad, 2);
    bool sym = (pad > 0) && !(fmin || fmax);
    int lo2 = sym ? lo - fdiv(pad, 2) : lo;
    int hi2 = sym ? hi + fdiv(1 + pad, 2) : hi;
    if ((pad > 0) && fmin) { lo2 = 0; hi2 = p; }
    if ((pad > 0) && fmax) { lo2 = s - p; hi2 = s; }
    lo = lo2; hi = hi2;
}

__device__ __forceinline__ float4 fmax4(float4 a, float4 b) {
    a.x = fmaxf(a.x, b.x); a.y = fmaxf(a.y, b.y);
    a.z = fmaxf(a.z, b.z); a.w = fmaxf(a.w, b.w);
    return a;
}

// Ballot build for suppression word w, rows [tlo,thi).
__device__ __forceinline__ void build_rows(int w, int tlo, int thi, int lane,
                                           const float* sx, const float* sy,
                                           const float* sx1, const float* sy1,
                                           const float* sarea,
                                           unsigned long long (*nsup)[3]) {
    const int j  = w * 64 + lane;
    const int jc = j < RR ? j : RR - 1;
    const float jx0 = sx[jc], jy0 = sy[jc], jx1 = sx1[jc], jy1 = sy1[jc], ja = sarea[jc];
    const bool jok = j < RR;

    #pragma unroll 4
    for (int t = tlo; t < thi; ++t) {
        const float xa = fmaxf(sx[t], jx0);
        const float ya = fmaxf(sy[t], jy0);
        const float xb = fminf(sx1[t], jx1);
        const float yb = fminf(sy1[t], jy1);
        const float iw  = fmaxf(__fsub_rn(xb, xa), 0.0f);
        const float ihh = fmaxf(__fsub_rn(yb, ya), 0.0f);
        const float inter = __fmul_rn(iw, ihh);
        const float denom = __fsub_rn(__fadd_rn(sarea[t], ja), inter);
        const bool pred = jok && (j > t) && (__fdiv_rn(inter, denom) > IOU_THRF);
        const unsigned long long bal = __ballot(pred);
        if (lane == 0) nsup[t][w] = ~bal;
    }
}

// R21 NMS, verbatim (best known): k0-only phase-1 build, wave-0-only
// early-exit scan, lazy phases 2/3 on the (rare) not-done path.
__global__ __launch_bounds__(1024)
void nms_clip_kernel(const float* __restrict__ roi, int* __restrict__ boxes_out) {
    const int b = blockIdx.x;
    const int tid = threadIdx.x;
    const int wid = tid >> 6;
    const int lane = tid & 63;

    __shared__ float sx[RR], sy[RR], sx1[RR], sy1[RR], sarea[RR];
    __shared__ unsigned long long nsup[RR][3];   // ~suppression words
    __shared__ int sdone;

    const float* rb = roi + (size_t)b * RR * 4;
    if (tid < RR) {
        const float4 r4 = reinterpret_cast<const float4*>(rb)[tid];
        sx[tid] = r4.x; sy[tid] = r4.y;
        sx1[tid] = __fadd_rn(r4.x, r4.z);
        sy1[tid] = __fadd_rn(r4.y, r4.w);
        sarea[tid] = __fmul_rn(r4.z, r4.w);
    }
    __syncthreads();

    // ---- phase 1 build: word 0 ONLY, rows [0,64): 16 waves x 4 rows ----
    build_rows(0, wid * 4, wid * 4 + 4, lane, sx, sy, sx1, sy1, sarea, nsup);
    __syncthreads();

    unsigned long long k0 = ~0ull, k1 = ~0ull, k2 = (1ull << 32) - 1;

    // ---- scan word 0, k0 only, WAVE 0 only ----
    if (wid == 0) {
        bool done = false;
        for (int tb = 0; tb < 64 && !done; tb += 8) {
            #pragma unroll
            for (int t0 = 0; t0 < 8; ++t0) {
                const int t = tb + t0;
                unsigned long long mb = ((k0 >> t) & 1ull) - 1ull;
                k0 &= nsup[t][0] | mb;
            }
            const unsigned long long pfx =
                (tb + 8 >= 64) ? ~0ull : ((1ull << (tb + 8)) - 1ull);
            if (__popcll(k0 & pfx) >= NREG) { k0 &= pfx; done = true; }
        }
        if (lane == 0) sdone = done ? 1 : 0;
    }
    __syncthreads();

    const int d0 = sdone;               // block-uniform
    if (d0) {
        k1 = 0; k2 = 0;                 // never read on the select path anyway
    } else {
        // ---- rare path. phase 2 build: rows [0,128) x words {1,2} ----
        {
            int w, tlo;
            if (wid < 8) { w = 1; tlo = wid * 16; }
            else         { w = 2; tlo = (wid - 8) * 16; }
            build_rows(w, tlo, tlo + 16, lane, sx, sy, sx1, sy1, sarea, nsup);
        }
        __syncthreads();

        if (wid == 0) {
            // exact k1/k2 reconstruction from FINAL k0 (linear, prefetchable)
            #pragma unroll 8
            for (int t = 0; t < 64; ++t) {
                unsigned long long mb = ((k0 >> t) & 1ull) - 1ull;
                k1 &= nsup[t][1] | mb;
                k2 &= nsup[t][2] | mb;
            }
            // scan word 1 with early exit
            bool done = false;
            const int cnt0 = __popcll(k0);
            for (int tb = 64; tb < 128 && !done; tb += 8) {
                #pragma unroll
                for (int t0 = 0; t0 < 8; ++t0) {
                    const int t = tb + t0;
                    unsigned long long mb = ((k1 >> (t - 64)) & 1ull) - 1ull;
                    k1 &= nsup[t][1] | mb;
                    k2 &= nsup[t][2] | mb;
                }
                const unsigned long long pfx =
                    (tb - 64 + 8 >= 64) ? ~0ull : ((1ull << (tb - 64 + 8)) - 1ull);
                if (cnt0 + __popcll(k1 & pfx) >= NREG) { k1 &= pfx; k2 = 0; done = true; }
            }
            if (lane == 0) sdone = done ? 1 : 0;
        }
        __syncthreads();

        const int d1 = sdone;           // block-uniform
        if (!d1) {
            // ---- phase 3 build: rows [128,159) word 2; 2 rows/wave ----
            {
                const int tlo = 128 + wid * 2;
                const int thi = min(tlo + 2, 159);
                if (tlo < 159)
                    build_rows(2, tlo, thi, lane, sx, sy, sx1, sy1, sarea, nsup);
            }
            __syncthreads();

            if (wid == 0) {
                bool done = false;
                const int cnt01 = __popcll(k0) + __popcll(k1);
                for (int tb = 128; tb < 159 && !done; tb += 8) {
                    const int te = (tb + 8 < 159) ? tb + 8 : 159;
                    for (int t = tb; t < te; ++t) {
                        unsigned long long mb = ((k2 >> (t - 128)) & 1ull) - 1ull;
                        k2 &= nsup[t][2] | mb;
                    }
                    const unsigned long long pfx =
                        ((te - 128) >= 64) ? ~0ull : ((1ull << (te - 128)) - 1ull);
                    if (cnt01 + __popcll(k2 & pfx) >= NREG) { k2 &= pfx; done = true; }
                }
            }
        }
    }

    if (tid >= NREG) return;            // select threads are all in wave 0

    // select the tid-th kept box (pad: box RR-1)
    int src = RR - 1;
    {
        int target = tid;
        unsigned long long words[3] = {k0, k1, k2};
        #pragma unroll
        for (int w = 0; w < 3; ++w) {
            int pc = __popcll(words[w]);
            if (target < pc) {
                unsigned long long x = words[w];
                for (int q = 0; q < target; ++q) x &= x - 1;
                src = w * 64 + (__ffsll((long long)x) - 1);
                break;
            }
            target -= pc;
        }
    }

    int x0 = max(0, (int)sx[src]);
    int y0 = max(0, (int)sy[src]);
    int x1 = min(WW, (int)sx1[src]);
    int y1 = min(HH, (int)sy1[src]);
    fix_span(x0, x1, PW, WW);
    fix_span(y0, y1, PH, HH);
    int* o = boxes_out + ((size_t)b * NREG + tid) * 4;
    o[0] = x0; o[1] = y0; o[2] = x1 - x0; o[3] = y1 - y0;
}

// R15/R21 pool (ILP-4), verbatim (best known; ILP-8 regressed in R22).
__global__ __launch_bounds__(PW * CC)
void pool_kernel(const float* __restrict__ feat, const int* __restrict__ boxes,
                 float* __restrict__ out) {
    // bijective XCD decode: xcd x = g%8 owns (b,n) pairs [x*16, x*16+16)
    const int g = blockIdx.x;
    const int x = g & 7;
    const int q = g >> 3;
    const int pair = x * 16 + q / 7;
    const int i = q % 7;
    const int n = pair & (NREG - 1);
    const int b = pair >> 5;

    const int wave = threadIdx.x >> 6;   // jj, 0..6 (wave-uniform)
    const int lane = threadIdx.x & 63;
    const int poff = lane >> 4;          // 0..3 pixel offset within group
    const int cq   = lane & 15;          // 0..15 channel quad

    const int4 bx = *reinterpret_cast<const int4*>(boxes + ((size_t)b * NREG + n) * 4);
    const int x0 = bx.x, y0 = bx.y, w = bx.z, h = bx.w;
    const int hs = h / PH, wsz = w / PW;

    const int r0 = y0 + i * hs;
    const int r1 = (i == PH - 1) ? (y0 + h) : (r0 + hs);
    const int c0 = x0 + wave * wsz;
    const int c1 = (wave == PW - 1) ? (x0 + w) : (c0 + wsz);
    const int nr = r1 - r0;              // 1..~10
    const int ng = (c1 - c0 + 3) >> 2;   // 1..4 column groups

    const float* fb = feat + (size_t)b * HH * WW * CC + (size_t)cq * 4;

    const float4 NEG = make_float4(-INFINITY, -INFINITY, -INFINITY, -INFINITY);
    float4 a0 = NEG, a1 = NEG, a2 = NEG, a3 = NEG;

    for (int gg = 0; gg < ng; ++gg) {
        int px = c0 + (gg << 2) + poff;
        px = px < c1 ? px : c1 - 1;
        const float* colp = fb + (size_t)px * CC;
        for (int rr = 0; rr < nr; rr += 4) {
            const int q1 = min(rr + 1, nr - 1);
            const int q2 = min(rr + 2, nr - 1);
            const int q3 = min(rr + 3, nr - 1);
            const float4 t0 = *reinterpret_cast<const float4*>(colp + (size_t)(r0 + rr) * (WW * CC));
            const float4 t1 = *reinterpret_cast<const float4*>(colp + (size_t)(r0 + q1) * (WW * CC));
            const float4 t2 = *reinterpret_cast<const float4*>(colp + (size_t)(r0 + q2) * (WW * CC));
            const float4 t3 = *reinterpret_cast<const float4*>(colp + (size_t)(r0 + q3) * (WW * CC));
            a0 = fmax4(a0, t0);
            a1 = fmax4(a1, t1);
            a2 = fmax4(a2, t2);
            a3 = fmax4(a3, t3);
        }
    }
    float4 v = fmax4(fmax4(a0, a1), fmax4(a2, a3));

    // reduce over the 4 pixel-groups: lanes {cq, cq+16, cq+32, cq+48}
    v.x = fmaxf(v.x, __shfl_xor(v.x, 16));
    v.y = fmaxf(v.y, __shfl_xor(v.y, 16));
    v.z = fmaxf(v.z, __shfl_xor(v.z, 16));
    v.w = fmaxf(v.w, __shfl_xor(v.w, 16));
    v.x = fmaxf(v.x, __shfl_xor(v.x, 32));
    v.y = fmaxf(v.y, __shfl_xor(v.y, 32));
    v.z = fmaxf(v.z, __shfl_xor(v.z, 32));
    v.w = fmaxf(v.w, __shfl_xor(v.w, 32));

    if (poff == 0) {
        float4* o = reinterpret_cast<float4*>(
            out + ((((size_t)b * NREG + n) * PH + i) * PW + wave) * CC) + cq;
        *o = v;
    }
}

extern "C" void kernel_launch(void* const* d_in, const int* in_sizes, int n_in,
                              void* d_out, int out_size, void* d_ws, size_t ws_size,
                              hipStream_t stream) {
    const float* features = (const float*)d_in[0];
    const float* roi      = (const float*)d_in[1];
    float* out = (float*)d_out;
    int* boxes = (int*)d_ws;   // BB*NREG*4 ints = 2 KB

    nms_clip_kernel<<<BB, 1024, 0, stream>>>(roi, boxes);
    pool_kernel<<<BB * NREG * PH, PW * CC, 0, stream>>>(features, boxes, out);
}